// Round 3
// baseline (736.403 us; speedup 1.0000x reference)
//
#include <hip/hip_runtime.h>
#include <float.h>

// Sparsemax attention, fp32 in/out. B=64, Lq=Lk=1024, D=64.
// d_out = out[B,Lq,D] ++ attn[B,Lq,Lk], fp32.
//
// R11 = R10 with the MASK FOLDED INTO THE SCORE KERNEL:
//   - score applies mask while quantizing acc->bf16: masked cells store
//     sentinel bf16 0xFF62 (~ -3.0e38). One aligned u32 (byte masks) or
//     int4 (int32 masks) load per (kt,g); mask lines reused 16x in-block.
//   - pv no longer reads mask at all (-64 MB HBM on the loaded kernel,
//     -4 NT loads - mask VALU per lane). Fully-masked check: mx <= -1e38.
//   - Numerics identical: p = max(0, s - tau) is exactly 0 for masked
//     cells with either -FLT_MAX or -3.0e38 sentinel.
// Proven R10 structure kept: two kernels (fusion hurt occupancy, R9),
// kprep_detect pre-swizzled K + DMA staging, swapped-operand MFMA with
// 8B packed S stores, shfl-broadcast sparse PV.

#define BATCH    64
#define SEQQ     1024
#define SEQK     1024
#define DHEAD    64

typedef short short8 __attribute__((ext_vector_type(8)));
typedef float f32x4  __attribute__((ext_vector_type(4)));
typedef unsigned short us4v __attribute__((ext_vector_type(4)));
typedef int int4v __attribute__((ext_vector_type(4)));

typedef const __attribute__((address_space(1))) unsigned int as1_cuint;
typedef __attribute__((address_space(3))) unsigned int as3_uint;
typedef __attribute__((address_space(3))) unsigned char as3_uchar;

__device__ __forceinline__ unsigned short bf16_rne(float f) {
    unsigned u = __float_as_uint(f);
    u += 0x7fffu + ((u >> 16) & 1u);
    return (unsigned short)(u >> 16);
}

__device__ __forceinline__ void cvt_hilo8(const float* fv, float scale,
                                          short8* hi, short8* lo) {
    #pragma unroll
    for (int j = 0; j < 8; ++j) {
        float f = fv[j] * scale;
        unsigned short hb = bf16_rne(f);
        float hf = __uint_as_float((unsigned)hb << 16);
        (*hi)[j] = (short)hb;
        (*lo)[j] = (short)bf16_rne(f - hf);
    }
}

// ---- standalone mask detector (fallback path only) ------------------------
__global__ void detect_mask_fmt(const unsigned char* __restrict__ m,
                                int* __restrict__ flag) {
    __shared__ int s_found;
    if (threadIdx.x == 0) s_found = 0;
    __syncthreads();
    int found = 0;
    for (int o = threadIdx.x; o < 65536; o += 256) {
        if ((o & 3) != 0 && m[o] != 0) found = 1;
    }
    if (found) atomicOr(&s_found, 1);
    __syncthreads();
    if (threadIdx.x == 0) *flag = s_found;   // 1 => bytes, 0 => int32
}

// ---- kernel 0: K -> hi/lo bf16 pre-swizzled (128-key tiles) + detect ------
__global__ __launch_bounds__(256) void kprep_detect(
        const float* __restrict__ k, unsigned short* __restrict__ kbuf,
        const unsigned char* __restrict__ m, int* __restrict__ flag) {
    if (blockIdx.x == (BATCH * SEQK * 8) / 256) {
        __shared__ int s_found;
        if (threadIdx.x == 0) s_found = 0;
        __syncthreads();
        int found = 0;
        for (int o = threadIdx.x; o < 65536; o += 256) {
            if ((o & 3) != 0 && m[o] != 0) found = 1;
        }
        if (found) atomicOr(&s_found, 1);
        __syncthreads();
        if (threadIdx.x == 0) *flag = s_found;
        return;
    }

    int gid  = blockIdx.x * 256 + threadIdx.x;    // [0, 64*1024*8)
    int db   = gid & 7;
    int keyg = (gid >> 3) & 1023;
    int b    = gid >> 13;
    int kt   = keyg >> 7;
    int key  = keyg & 127;

    const float4* src =
        (const float4*)(k + ((size_t)b * SEQK + keyg) * DHEAD + db * 8);
    float4 f0 = src[0], f1 = src[1];
    float fv[8] = {f0.x, f0.y, f0.z, f0.w, f1.x, f1.y, f1.z, f1.w};
    short8 hi, lo;
    cvt_hilo8(fv, 1.0f, &hi, &lo);

    unsigned short* tile = kbuf + (size_t)(b * 8 + kt) * 16384;
    int off = key * 64 + ((db ^ (key & 7)) * 8);   // ushort units
    *(short8*)(tile + off)        = hi;
    *(short8*)(tile + 8192 + off) = lo;
}

// ---- kernel A (fast path): scores via MFMA, DMA-staged K, mask folded -----
// grid 1024: x = qt*64 + b (x%8 = b%8 -> per-batch XCD pinning).
// Swapped operands: C row = key (quad*4+r), col = q (l15) -> 8B stores.
// Masked cells store SENT (~ -3.0e38 bf16) so pv never touches the mask.
__global__ __launch_bounds__(256) void score_kernel_dma(
        const float* __restrict__ q, const unsigned short* __restrict__ kbuf,
        const void* __restrict__ mask, const int* __restrict__ fmt_flag,
        unsigned short* __restrict__ sbuf, int pitch) {
    const int lane = threadIdx.x & 63;
    const int wave = threadIdx.x >> 6;
    const int quad = lane >> 4;
    const int l15  = lane & 15;
    const int qt = blockIdx.x >> 6;
    const int b  = blockIdx.x & 63;
    const int mask_is_byte = fmt_flag ? *fmt_flag : 1;
    const unsigned short SENT = bf16_rne(-3.0e38f);

    __shared__ unsigned short klds[2 * 128 * 64];   // 32 KB

    // Q B-frags once, scaled by 1/8, hi/lo split
    const int qg = qt * 64 + wave * 16 + l15;       // this lane's q-row
    const float* qrow = q + ((size_t)b * SEQQ + qg) * DHEAD;
    short8 a_hi[2], a_lo[2];
    #pragma unroll
    for (int kc = 0; kc < 2; ++kc) {
        const float4* src = (const float4*)(qrow + kc * 32 + quad * 8);
        float4 f0 = src[0], f1 = src[1];
        float fv[8] = {f0.x, f0.y, f0.z, f0.w, f1.x, f1.y, f1.z, f1.w};
        cvt_hilo8(fv, 0.125f, &a_hi[kc], &a_lo[kc]);
    }

    const size_t mrow = (size_t)b * SEQQ + qg;      // mask row index
    unsigned short* srowq = sbuf + mrow * (size_t)pitch;

    for (int kt = 0; kt < 8; ++kt) {
        __syncthreads();   // guard klds reuse across kt iterations
        // DMA 32 KB tile: 4 waves x 8 calls x (64 lanes x 16 B)
        const unsigned char* gtile =
            (const unsigned char*)(kbuf + (size_t)(b * 8 + kt) * 16384);
        {
            unsigned base = wave * 8192 + lane * 16;
            #pragma unroll
            for (int j = 0; j < 8; ++j) {
                unsigned off = base + j * 1024;
                as1_cuint* gp = (as1_cuint*)(gtile + off);
                as3_uint*  lp = (as3_uint*)((as3_uchar*)klds +
                                            (wave * 8192 + j * 1024));
                __builtin_amdgcn_global_load_lds(gp, lp, 16, 0, 0);
            }
        }
        __syncthreads();

        #pragma unroll
        for (int g = 0; g < 8; ++g) {
            int key = g * 16 + l15;
            short8 b_hi[2], b_lo[2];
            #pragma unroll
            for (int kc = 0; kc < 2; ++kc) {
                int db  = kc * 4 + quad;
                int off = key * 64 + ((db ^ (key & 7)) * 8);
                b_hi[kc] = *(const short8*)(klds + off);
                b_lo[kc] = *(const short8*)(klds + 8192 + off);
            }
            f32x4 acc = {0.f, 0.f, 0.f, 0.f};
            #pragma unroll
            for (int kc = 0; kc < 2; ++kc) {
                acc = __builtin_amdgcn_mfma_f32_16x16x32_bf16(b_hi[kc], a_hi[kc], acc, 0, 0, 0);
                acc = __builtin_amdgcn_mfma_f32_16x16x32_bf16(b_hi[kc], a_lo[kc], acc, 0, 0, 0);
                acc = __builtin_amdgcn_mfma_f32_16x16x32_bf16(b_lo[kc], a_hi[kc], acc, 0, 0, 0);
            }
            // this lane's 4 keys of row qg: kt*128 + g*16 + quad*4 .. +3
            int kbase = kt * 128 + g * 16 + quad * 4;
            us4v pk;
            if (mask_is_byte) {
                unsigned mw = *(const unsigned*)(
                    (const unsigned char*)mask + mrow * SEQK + kbase);
                #pragma unroll
                for (int r = 0; r < 4; ++r)
                    pk[r] = ((mw >> (8 * r)) & 0xffu) ? SENT
                                                      : bf16_rne(acc[r]);
            } else {
                int4v mi = *(const int4v*)(
                    (const int*)mask + mrow * SEQK + kbase);
                #pragma unroll
                for (int r = 0; r < 4; ++r)
                    pk[r] = mi[r] ? SENT : bf16_rne(acc[r]);
            }
            *(us4v*)(srowq + kbase) = pk;
        }
    }
}

// ---- kernel A (fallback): cvt-in-loop version, same swapped+masked layout -
__global__ __launch_bounds__(256) void score_kernel_cvt(
        const float* __restrict__ q, const float* __restrict__ k,
        const void* __restrict__ mask, const int* __restrict__ fmt_flag,
        unsigned short* __restrict__ sbuf, int pitch) {
    const int lane = threadIdx.x & 63;
    const int wave = threadIdx.x >> 6;
    const int quad = lane >> 4;
    const int l15  = lane & 15;
    const int qt = blockIdx.x >> 6;
    const int b  = blockIdx.x & 63;
    const int mask_is_byte = fmt_flag ? *fmt_flag : 1;
    const unsigned short SENT = bf16_rne(-3.0e38f);

    __shared__ unsigned short klds[2 * 128 * 64];

    const int qg = qt * 64 + wave * 16 + l15;
    const float* qrow = q + ((size_t)b * SEQQ + qg) * DHEAD;
    short8 a_hi[2], a_lo[2];
    #pragma unroll
    for (int kc = 0; kc < 2; ++kc) {
        const float4* src = (const float4*)(qrow + kc * 32 + quad * 8);
        float4 f0 = src[0], f1 = src[1];
        float fv[8] = {f0.x, f0.y, f0.z, f0.w, f1.x, f1.y, f1.z, f1.w};
        cvt_hilo8(fv, 0.125f, &a_hi[kc], &a_lo[kc]);
    }

    const float* kb = k + (size_t)b * SEQK * DHEAD;
    const size_t mrow = (size_t)b * SEQQ + qg;
    unsigned short* srowq = sbuf + mrow * (size_t)pitch;

    for (int kt = 0; kt < 8; ++kt) {
        __syncthreads();
        const float* kbase_p = kb + (size_t)kt * 128 * DHEAD;
        #pragma unroll
        for (int it = 0; it < 4; ++it) {
            int e   = threadIdx.x + 256 * it;
            int key = e >> 3, db = e & 7;
            const float4* src = (const float4*)(kbase_p + key * DHEAD + db * 8);
            float4 f0 = src[0], f1 = src[1];
            float fv[8] = {f0.x, f0.y, f0.z, f0.w, f1.x, f1.y, f1.z, f1.w};
            short8 hi, lo;
            cvt_hilo8(fv, 1.0f, &hi, &lo);
            int off = key * 64 + ((db ^ (key & 7)) * 8);
            *(short8*)(klds + off)        = hi;
            *(short8*)(klds + 8192 + off) = lo;
        }
        __syncthreads();

        #pragma unroll
        for (int g = 0; g < 8; ++g) {
            int key = g * 16 + l15;
            short8 b_hi[2], b_lo[2];
            #pragma unroll
            for (int kc = 0; kc < 2; ++kc) {
                int db  = kc * 4 + quad;
                int off = key * 64 + ((db ^ (key & 7)) * 8);
                b_hi[kc] = *(const short8*)(klds + off);
                b_lo[kc] = *(const short8*)(klds + 8192 + off);
            }
            f32x4 acc = {0.f, 0.f, 0.f, 0.f};
            #pragma unroll
            for (int kc = 0; kc < 2; ++kc) {
                acc = __builtin_amdgcn_mfma_f32_16x16x32_bf16(b_hi[kc], a_hi[kc], acc, 0, 0, 0);
                acc = __builtin_amdgcn_mfma_f32_16x16x32_bf16(b_hi[kc], a_lo[kc], acc, 0, 0, 0);
                acc = __builtin_amdgcn_mfma_f32_16x16x32_bf16(b_lo[kc], a_hi[kc], acc, 0, 0, 0);
            }
            int kb4 = kt * 128 + g * 16 + quad * 4;
            us4v pk;
            if (mask_is_byte) {
                unsigned mw = *(const unsigned*)(
                    (const unsigned char*)mask + mrow * SEQK + kb4);
                #pragma unroll
                for (int r = 0; r < 4; ++r)
                    pk[r] = ((mw >> (8 * r)) & 0xffu) ? SENT
                                                      : bf16_rne(acc[r]);
            } else {
                int4v mi = *(const int4v*)(
                    (const int*)mask + mrow * SEQK + kb4);
                #pragma unroll
                for (int r = 0; r < 4; ++r)
                    pk[r] = mi[r] ? SENT : bf16_rne(acc[r]);
            }
            *(us4v*)(srowq + kb4) = pk;
        }
    }
}

// ---- kernel B: sparsemax + sparse PV, one wave per row, NO mask access ----
__global__ __launch_bounds__(256) void sparsemax_pv(
        const float* __restrict__ v,
        float* __restrict__ out, float* __restrict__ attn,
        const unsigned short* __restrict__ sbuf, int pitch) {
    const int lane = threadIdx.x & 63;
    const int wave = threadIdx.x >> 6;
    const int row  = blockIdx.x * 4 + wave;
    const int b    = row >> 10;
    float* arow = attn + (size_t)row * SEQK;

    // lane holds keys 4*lane + 256*t + c (coalesced 8B, nontemporal)
    const us4v* s4 = (const us4v*)(sbuf + (size_t)row * (size_t)pitch);
    float s[16];
    #pragma unroll
    for (int t = 0; t < 4; ++t) {
        us4v u = __builtin_nontemporal_load(s4 + lane + 64 * t);
        s[4*t+0] = __uint_as_float((unsigned)u[0] << 16);
        s[4*t+1] = __uint_as_float((unsigned)u[1] << 16);
        s[4*t+2] = __uint_as_float((unsigned)u[2] << 16);
        s[4*t+3] = __uint_as_float((unsigned)u[3] << 16);
    }

    float mx = -FLT_MAX;
    #pragma unroll
    for (int i = 0; i < 16; ++i) mx = fmaxf(mx, s[i]);
    #pragma unroll
    for (int off = 32; off >= 1; off >>= 1)
        mx = fmaxf(mx, __shfl_xor(mx, off, 64));

    if (mx <= -1.0e38f) {   // fully masked row (all sentinels) -> zeros
        f32x4 z = {0.f, 0.f, 0.f, 0.f};
        #pragma unroll
        for (int t = 0; t < 4; ++t)
            __builtin_nontemporal_store(z, (f32x4*)arow + lane + 64 * t);
        out[(size_t)row * DHEAD + lane] = 0.f;
        return;
    }

    // Michelot: seed thr = mx-1 (tau* >= mx-1); shrinks to exact support.
    float thr = mx - 1.0f, tau = 0.f;
    int cnt_prev = -1;
    for (int it = 0; it < 32; ++it) {
        float lsum = 0.f; int lcnt = 0;
        #pragma unroll
        for (int i = 0; i < 16; ++i)
            if (s[i] > thr) { lsum += s[i]; lcnt++; }
        #pragma unroll
        for (int off = 32; off >= 1; off >>= 1) {
            lsum += __shfl_xor(lsum, off, 64);
            lcnt += __shfl_xor(lcnt, off, 64);
        }
        tau = (lsum - 1.0f) / (float)lcnt;
        if (lcnt == cnt_prev) break;
        cnt_prev = lcnt;
        thr = tau;
    }

    // p; attn NT-store
    float p[16];
    #pragma unroll
    for (int i = 0; i < 16; ++i) {
        float pv = s[i] - tau;
        p[i] = pv > 0.f ? pv : 0.f;
    }
    #pragma unroll
    for (int t = 0; t < 4; ++t) {
        f32x4 f = {p[4*t+0], p[4*t+1], p[4*t+2], p[4*t+3]};
        __builtin_nontemporal_store(f, (f32x4*)arow + lane + 64 * t);
    }

    // sparse PV: group-of-4 extraction; p broadcast via __shfl
    // (k0..k3 wave-uniform -> readlane).
    const float* vbase = v + (size_t)b * SEQK * DHEAD;
    float oacc = 0.f;
    #pragma unroll
    for (int t = 0; t < 4; ++t) {
        #pragma unroll
        for (int c = 0; c < 4; ++c) {
            int i = 4 * t + c;
            unsigned long long mb = __ballot(p[i] > 0.f);
            while (mb) {
                int k0, k1 = -1, k2 = -1, k3 = -1;
                k0 = __ffsll(mb) - 1; mb &= mb - 1;
                if (mb) { k1 = __ffsll(mb) - 1; mb &= mb - 1; }
                if (mb) { k2 = __ffsll(mb) - 1; mb &= mb - 1; }
                if (mb) { k3 = __ffsll(mb) - 1; mb &= mb - 1; }
                float pj0 = __shfl(p[i], k0);
                float v0  = vbase[(size_t)(4 * k0 + 256 * t + c) * DHEAD + lane];
                float pj1 = 0.f, pj2 = 0.f, pj3 = 0.f;
                float v1 = 0.f, v2 = 0.f, v3 = 0.f;
                if (k1 >= 0) {
                    pj1 = __shfl(p[i], k1);
                    v1  = vbase[(size_t)(4 * k1 + 256 * t + c) * DHEAD + lane];
                }
                if (k2 >= 0) {
                    pj2 = __shfl(p[i], k2);
                    v2  = vbase[(size_t)(4 * k2 + 256 * t + c) * DHEAD + lane];
                }
                if (k3 >= 0) {
                    pj3 = __shfl(p[i], k3);
                    v3  = vbase[(size_t)(4 * k3 + 256 * t + c) * DHEAD + lane];
                }
                oacc = fmaf(pj0, v0, oacc);
                if (k1 >= 0) oacc = fmaf(pj1, v1, oacc);
                if (k2 >= 0) oacc = fmaf(pj2, v2, oacc);
                if (k3 >= 0) oacc = fmaf(pj3, v3, oacc);
            }
        }
    }
    out[(size_t)row * DHEAD + lane] = oacc;
}

extern "C" void kernel_launch(void* const* d_in, const int* in_sizes, int n_in,
                              void* d_out, int out_size, void* d_ws, size_t ws_size,
                              hipStream_t stream) {
    const float* q = (const float*)d_in[0];
    const float* k = (const float*)d_in[1];
    const float* v = (const float*)d_in[2];
    const void*  m = d_in[3];

    float* out  = (float*)d_out;
    float* attn = out + (size_t)BATCH * SEQQ * DHEAD;

    int* flag = nullptr;
    if (ws_size >= sizeof(int)) flag = (int*)d_ws;

    // ws layout: [0,16) flag | [16, 16+S) S bf16 | [16+S, 16+S+K) K hi/lo
    const size_t S_BYTES = (size_t)BATCH * SEQQ * SEQK * 2;          // 134 MB
    const size_t K_BYTES = (size_t)BATCH * SEQK * DHEAD * 2 * 2;     // 16 MB

    unsigned short* sbuf;
    int pitch;
    bool s_in_ws = ws_size >= 16 + S_BYTES;
    if (s_in_ws) {
        sbuf  = (unsigned short*)d_ws + 8;
        pitch = SEQK;
    } else {
        sbuf  = (unsigned short*)attn;   // in-place, strided (proven R5)
        pitch = 2 * SEQK;
    }

    bool k_in_ws = s_in_ws && ws_size >= 16 + S_BYTES + K_BYTES;
    if (k_in_ws) {
        unsigned short* kbuf =
            (unsigned short*)((char*)d_ws + 16 + S_BYTES);
        // kprep + mask-format detect fused: one extra block does detect
        kprep_detect<<<(BATCH * SEQK * 8) / 256 + 1, 256, 0, stream>>>(
            k, kbuf, (const unsigned char*)m, flag);
        score_kernel_dma<<<(SEQQ / 64) * BATCH, 256, 0, stream>>>(
            q, kbuf, m, flag, sbuf, pitch);
    } else {
        if (flag)
            detect_mask_fmt<<<1, 256, 0, stream>>>((const unsigned char*)m, flag);
        score_kernel_cvt<<<(SEQQ / 64) * BATCH, 256, 0, stream>>>(
            q, k, m, flag, sbuf, pitch);
    }

    sparsemax_pv<<<(BATCH * SEQQ) / 4, 256, 0, stream>>>(
        v, out, attn, sbuf, pitch);
}

// Round 5
// 710.375 us; speedup vs baseline: 1.0366x; 1.0366x over previous
//
#include <hip/hip_runtime.h>
#include <float.h>

// Sparsemax attention, fp32 in/out. B=64, Lq=Lk=1024, D=64.
// d_out = out[B,Lq,D] ++ attn[B,Lq,Lk], fp32.
//
// R12 (resubmit; previous round hit GPUAcquisitionTimeout, no data) =
// R10 (proven 638.8 us) with score's LDS staging REMOVED:
//   - K fragments are loaded straight from the pre-swizzled kbuf into
//     registers. Per XCD, the resident blocks' K working set is
//     8 batches x 256 KB = 2 MB < 4 MB L2 (XCD-pinned grid), so these
//     are L2 hits; with no barriers and 0 LDS the loop is free-running
//     and TLP/ILP hide the ~200cyc L2 latency. (Guide common-mistake #7:
//     don't LDS-stage what L2-fits -- R11's counters showed score was
//     latency-bound on the staging cycle: MfmaUtil 4.8, VALU 7.4, all idle.)
//   - kprep drops the XOR bank-swizzle (only existed for LDS banking).
//   - R11's mask-in-score REVERTED (it put scattered HBM-latency mask
//     reads inside the MFMA loop: score 207 us). Mask back in pv as
//     coalesced NT loads (R10's proven form).
// Kept from R8/R10: two-kernel structure, kprep+detect fusion, swapped
// MFMA operands w/ 8B packed S stores, shfl-broadcast sparse PV.

#define BATCH    64
#define SEQQ     1024
#define SEQK     1024
#define DHEAD    64

typedef short short8 __attribute__((ext_vector_type(8)));
typedef float f32x4  __attribute__((ext_vector_type(4)));
typedef unsigned short us4v __attribute__((ext_vector_type(4)));

__device__ __forceinline__ unsigned short bf16_rne(float f) {
    unsigned u = __float_as_uint(f);
    u += 0x7fffu + ((u >> 16) & 1u);
    return (unsigned short)(u >> 16);
}

__device__ __forceinline__ void cvt_hilo8(const float* fv, float scale,
                                          short8* hi, short8* lo) {
    #pragma unroll
    for (int j = 0; j < 8; ++j) {
        float f = fv[j] * scale;
        unsigned short hb = bf16_rne(f);
        float hf = __uint_as_float((unsigned)hb << 16);
        (*hi)[j] = (short)hb;
        (*lo)[j] = (short)bf16_rne(f - hf);
    }
}

// ---- standalone mask detector (fallback path only) ------------------------
__global__ void detect_mask_fmt(const unsigned char* __restrict__ m,
                                int* __restrict__ flag) {
    __shared__ int s_found;
    if (threadIdx.x == 0) s_found = 0;
    __syncthreads();
    int found = 0;
    for (int o = threadIdx.x; o < 65536; o += 256) {
        if ((o & 3) != 0 && m[o] != 0) found = 1;
    }
    if (found) atomicOr(&s_found, 1);
    __syncthreads();
    if (threadIdx.x == 0) *flag = s_found;   // 1 => bytes, 0 => int32
}

// ---- kernel 0: K -> hi/lo bf16, linear layout (no swizzle) + detect -------
// kbuf tile (b,kt): 16384 ushorts = [hi: key(128) x d(64)][lo: same].
// off = key*64 + db*8. Last block runs the mask-format detector.
__global__ __launch_bounds__(256) void kprep_detect(
        const float* __restrict__ k, unsigned short* __restrict__ kbuf,
        const unsigned char* __restrict__ m, int* __restrict__ flag) {
    if (blockIdx.x == (BATCH * SEQK * 8) / 256) {
        __shared__ int s_found;
        if (threadIdx.x == 0) s_found = 0;
        __syncthreads();
        int found = 0;
        for (int o = threadIdx.x; o < 65536; o += 256) {
            if ((o & 3) != 0 && m[o] != 0) found = 1;
        }
        if (found) atomicOr(&s_found, 1);
        __syncthreads();
        if (threadIdx.x == 0) *flag = s_found;
        return;
    }

    int gid  = blockIdx.x * 256 + threadIdx.x;    // [0, 64*1024*8)
    int db   = gid & 7;
    int keyg = (gid >> 3) & 1023;
    int b    = gid >> 13;
    int kt   = keyg >> 7;
    int key  = keyg & 127;

    const float4* src =
        (const float4*)(k + ((size_t)b * SEQK + keyg) * DHEAD + db * 8);
    float4 f0 = src[0], f1 = src[1];
    float fv[8] = {f0.x, f0.y, f0.z, f0.w, f1.x, f1.y, f1.z, f1.w};
    short8 hi, lo;
    cvt_hilo8(fv, 1.0f, &hi, &lo);

    unsigned short* tile = kbuf + (size_t)(b * 8 + kt) * 16384;
    int off = key * 64 + db * 8;                   // linear, ushort units
    *(short8*)(tile + off)        = hi;
    *(short8*)(tile + 8192 + off) = lo;
}

// ---- kernel A (fast path): scores via MFMA, K frags direct from L2 --------
// grid 1024: x = qt*64 + b (x%8 = b%8 -> per-batch XCD pinning).
// Swapped operands: C row = key (quad*4+r), col = q (l15) -> 8B stores.
// No LDS, no barriers: each lane reads its own 16B fragments from kbuf.
__global__ __launch_bounds__(256) void score_kernel_direct(
        const float* __restrict__ q, const unsigned short* __restrict__ kbuf,
        unsigned short* __restrict__ sbuf, int pitch) {
    const int lane = threadIdx.x & 63;
    const int wave = threadIdx.x >> 6;
    const int quad = lane >> 4;
    const int l15  = lane & 15;
    const int qt = blockIdx.x >> 6;
    const int b  = blockIdx.x & 63;

    // Q B-frags once, scaled by 1/8, hi/lo split
    const int qg = qt * 64 + wave * 16 + l15;       // this lane's q-row
    const float* qrow = q + ((size_t)b * SEQQ + qg) * DHEAD;
    short8 a_hi[2], a_lo[2];
    #pragma unroll
    for (int kc = 0; kc < 2; ++kc) {
        const float4* src = (const float4*)(qrow + kc * 32 + quad * 8);
        float4 f0 = src[0], f1 = src[1];
        float fv[8] = {f0.x, f0.y, f0.z, f0.w, f1.x, f1.y, f1.z, f1.w};
        cvt_hilo8(fv, 0.125f, &a_hi[kc], &a_lo[kc]);
    }

    unsigned short* srowq =
        sbuf + ((size_t)b * SEQQ + qg) * (size_t)pitch;
    const unsigned short* kb_b = kbuf + (size_t)b * 8 * 16384;

    for (int kt = 0; kt < 8; ++kt) {
        const unsigned short* tile = kb_b + kt * 16384;
        #pragma unroll
        for (int g = 0; g < 8; ++g) {
            int key = g * 16 + l15;
            short8 b_hi[2], b_lo[2];
            #pragma unroll
            for (int kc = 0; kc < 2; ++kc) {
                int off = key * 64 + (kc * 4 + quad) * 8;   // linear
                b_hi[kc] = *(const short8*)(tile + off);
                b_lo[kc] = *(const short8*)(tile + 8192 + off);
            }
            f32x4 acc = {0.f, 0.f, 0.f, 0.f};
            #pragma unroll
            for (int kc = 0; kc < 2; ++kc) {
                acc = __builtin_amdgcn_mfma_f32_16x16x32_bf16(b_hi[kc], a_hi[kc], acc, 0, 0, 0);
                acc = __builtin_amdgcn_mfma_f32_16x16x32_bf16(b_hi[kc], a_lo[kc], acc, 0, 0, 0);
                acc = __builtin_amdgcn_mfma_f32_16x16x32_bf16(b_lo[kc], a_hi[kc], acc, 0, 0, 0);
            }
            // C layout (swapped): row = quad*4+r -> key, col = l15 -> q
            us4v pk;
            #pragma unroll
            for (int r = 0; r < 4; ++r) pk[r] = bf16_rne(acc[r]);
            *(us4v*)(srowq + kt * 128 + g * 16 + quad * 4) = pk;
        }
    }
}

// ---- kernel A (fallback): cvt-in-loop version w/ LDS (self-contained) -----
__global__ __launch_bounds__(256) void score_kernel_cvt(
        const float* __restrict__ q, const float* __restrict__ k,
        unsigned short* __restrict__ sbuf, int pitch) {
    const int lane = threadIdx.x & 63;
    const int wave = threadIdx.x >> 6;
    const int quad = lane >> 4;
    const int l15  = lane & 15;
    const int qt = blockIdx.x >> 6;
    const int b  = blockIdx.x & 63;

    __shared__ unsigned short klds[2 * 128 * 64];

    const float* qrow =
        q + ((size_t)b * SEQQ + qt * 64 + wave * 16 + l15) * DHEAD;
    short8 a_hi[2], a_lo[2];
    #pragma unroll
    for (int kc = 0; kc < 2; ++kc) {
        const float4* src = (const float4*)(qrow + kc * 32 + quad * 8);
        float4 f0 = src[0], f1 = src[1];
        float fv[8] = {f0.x, f0.y, f0.z, f0.w, f1.x, f1.y, f1.z, f1.w};
        cvt_hilo8(fv, 0.125f, &a_hi[kc], &a_lo[kc]);
    }

    const float* kb = k + (size_t)b * SEQK * DHEAD;
    unsigned short* srowq =
        sbuf + ((size_t)b * SEQQ + qt * 64 + wave * 16 + l15) * (size_t)pitch;

    for (int kt = 0; kt < 8; ++kt) {
        __syncthreads();
        const float* kbase = kb + (size_t)kt * 128 * DHEAD;
        #pragma unroll
        for (int it = 0; it < 4; ++it) {
            int e   = threadIdx.x + 256 * it;
            int key = e >> 3, db = e & 7;
            const float4* src = (const float4*)(kbase + key * DHEAD + db * 8);
            float4 f0 = src[0], f1 = src[1];
            float fv[8] = {f0.x, f0.y, f0.z, f0.w, f1.x, f1.y, f1.z, f1.w};
            short8 hi, lo;
            cvt_hilo8(fv, 1.0f, &hi, &lo);
            int off = key * 64 + ((db ^ (key & 7)) * 8);
            *(short8*)(klds + off)        = hi;
            *(short8*)(klds + 8192 + off) = lo;
        }
        __syncthreads();

        #pragma unroll
        for (int g = 0; g < 8; ++g) {
            int key = g * 16 + l15;
            short8 b_hi[2], b_lo[2];
            #pragma unroll
            for (int kc = 0; kc < 2; ++kc) {
                int db  = kc * 4 + quad;
                int off = key * 64 + ((db ^ (key & 7)) * 8);
                b_hi[kc] = *(const short8*)(klds + off);
                b_lo[kc] = *(const short8*)(klds + 8192 + off);
            }
            f32x4 acc = {0.f, 0.f, 0.f, 0.f};
            #pragma unroll
            for (int kc = 0; kc < 2; ++kc) {
                acc = __builtin_amdgcn_mfma_f32_16x16x32_bf16(b_hi[kc], a_hi[kc], acc, 0, 0, 0);
                acc = __builtin_amdgcn_mfma_f32_16x16x32_bf16(b_hi[kc], a_lo[kc], acc, 0, 0, 0);
                acc = __builtin_amdgcn_mfma_f32_16x16x32_bf16(b_lo[kc], a_hi[kc], acc, 0, 0, 0);
            }
            us4v pk;
            #pragma unroll
            for (int r = 0; r < 4; ++r) pk[r] = bf16_rne(acc[r]);
            *(us4v*)(srowq + kt * 128 + g * 16 + quad * 4) = pk;
        }
    }
}

// ---- kernel B: sparsemax + sparse PV, one wave per row, zero LDS ----------
__global__ __launch_bounds__(256) void sparsemax_pv(
        const float* __restrict__ v, const void* __restrict__ mask,
        const int* __restrict__ fmt_flag,
        float* __restrict__ out, float* __restrict__ attn,
        const unsigned short* __restrict__ sbuf, int pitch) {
    const int lane = threadIdx.x & 63;
    const int wave = threadIdx.x >> 6;
    const int row  = blockIdx.x * 4 + wave;
    const int b    = row >> 10;
    float* arow = attn + (size_t)row * SEQK;
    const int mask_is_byte = fmt_flag ? *fmt_flag : 1;

    // lane holds keys 4*lane + 256*t + c (coalesced 8B, nontemporal)
    const us4v* s4 = (const us4v*)(sbuf + (size_t)row * (size_t)pitch);
    float s[16];
    #pragma unroll
    for (int t = 0; t < 4; ++t) {
        us4v u = __builtin_nontemporal_load(s4 + lane + 64 * t);
        s[4*t+0] = __uint_as_float((unsigned)u[0] << 16);
        s[4*t+1] = __uint_as_float((unsigned)u[1] << 16);
        s[4*t+2] = __uint_as_float((unsigned)u[2] << 16);
        s[4*t+3] = __uint_as_float((unsigned)u[3] << 16);
    }
    if (mask_is_byte) {
        const unsigned* m32 =
            (const unsigned*)((const unsigned char*)mask + (size_t)row * SEQK);
        #pragma unroll
        for (int t = 0; t < 4; ++t) {
            unsigned m = __builtin_nontemporal_load(m32 + lane + 64 * t);
            if (m & 0x000000ffu) s[4*t+0] = -FLT_MAX;
            if (m & 0x0000ff00u) s[4*t+1] = -FLT_MAX;
            if (m & 0x00ff0000u) s[4*t+2] = -FLT_MAX;
            if (m & 0xff000000u) s[4*t+3] = -FLT_MAX;
        }
    } else {
        const int* mi = (const int*)mask + (size_t)row * SEQK;
        #pragma unroll
        for (int t = 0; t < 4; ++t) {
            int m0 = __builtin_nontemporal_load(mi + 4 * (lane + 64 * t) + 0);
            int m1 = __builtin_nontemporal_load(mi + 4 * (lane + 64 * t) + 1);
            int m2 = __builtin_nontemporal_load(mi + 4 * (lane + 64 * t) + 2);
            int m3 = __builtin_nontemporal_load(mi + 4 * (lane + 64 * t) + 3);
            if (m0) s[4*t+0] = -FLT_MAX;
            if (m1) s[4*t+1] = -FLT_MAX;
            if (m2) s[4*t+2] = -FLT_MAX;
            if (m3) s[4*t+3] = -FLT_MAX;
        }
    }

    float mx = -FLT_MAX;
    #pragma unroll
    for (int i = 0; i < 16; ++i) mx = fmaxf(mx, s[i]);
    #pragma unroll
    for (int off = 32; off >= 1; off >>= 1)
        mx = fmaxf(mx, __shfl_xor(mx, off, 64));

    if (mx <= -FLT_MAX) {   // fully masked row -> zeros
        f32x4 z = {0.f, 0.f, 0.f, 0.f};
        #pragma unroll
        for (int t = 0; t < 4; ++t)
            __builtin_nontemporal_store(z, (f32x4*)arow + lane + 64 * t);
        out[(size_t)row * DHEAD + lane] = 0.f;
        return;
    }

    // Michelot: seed thr = mx-1 (tau* >= mx-1); shrinks to exact support.
    float thr = mx - 1.0f, tau = 0.f;
    int cnt_prev = -1;
    for (int it = 0; it < 32; ++it) {
        float lsum = 0.f; int lcnt = 0;
        #pragma unroll
        for (int i = 0; i < 16; ++i)
            if (s[i] > thr) { lsum += s[i]; lcnt++; }
        #pragma unroll
        for (int off = 32; off >= 1; off >>= 1) {
            lsum += __shfl_xor(lsum, off, 64);
            lcnt += __shfl_xor(lcnt, off, 64);
        }
        tau = (lsum - 1.0f) / (float)lcnt;
        if (lcnt == cnt_prev) break;
        cnt_prev = lcnt;
        thr = tau;
    }

    // p; attn NT-store
    float p[16];
    #pragma unroll
    for (int i = 0; i < 16; ++i) {
        float pv = s[i] - tau;
        p[i] = pv > 0.f ? pv : 0.f;
    }
    #pragma unroll
    for (int t = 0; t < 4; ++t) {
        f32x4 f = {p[4*t+0], p[4*t+1], p[4*t+2], p[4*t+3]};
        __builtin_nontemporal_store(f, (f32x4*)arow + lane + 64 * t);
    }

    // sparse PV: group-of-4 extraction; p broadcast via __shfl
    // (k0..k3 wave-uniform -> readlane).
    const float* vbase = v + (size_t)b * SEQK * DHEAD;
    float oacc = 0.f;
    #pragma unroll
    for (int t = 0; t < 4; ++t) {
        #pragma unroll
        for (int c = 0; c < 4; ++c) {
            int i = 4 * t + c;
            unsigned long long mb = __ballot(p[i] > 0.f);
            while (mb) {
                int k0, k1 = -1, k2 = -1, k3 = -1;
                k0 = __ffsll(mb) - 1; mb &= mb - 1;
                if (mb) { k1 = __ffsll(mb) - 1; mb &= mb - 1; }
                if (mb) { k2 = __ffsll(mb) - 1; mb &= mb - 1; }
                if (mb) { k3 = __ffsll(mb) - 1; mb &= mb - 1; }
                float pj0 = __shfl(p[i], k0);
                float v0  = vbase[(size_t)(4 * k0 + 256 * t + c) * DHEAD + lane];
                float pj1 = 0.f, pj2 = 0.f, pj3 = 0.f;
                float v1 = 0.f, v2 = 0.f, v3 = 0.f;
                if (k1 >= 0) {
                    pj1 = __shfl(p[i], k1);
                    v1  = vbase[(size_t)(4 * k1 + 256 * t + c) * DHEAD + lane];
                }
                if (k2 >= 0) {
                    pj2 = __shfl(p[i], k2);
                    v2  = vbase[(size_t)(4 * k2 + 256 * t + c) * DHEAD + lane];
                }
                if (k3 >= 0) {
                    pj3 = __shfl(p[i], k3);
                    v3  = vbase[(size_t)(4 * k3 + 256 * t + c) * DHEAD + lane];
                }
                oacc = fmaf(pj0, v0, oacc);
                if (k1 >= 0) oacc = fmaf(pj1, v1, oacc);
                if (k2 >= 0) oacc = fmaf(pj2, v2, oacc);
                if (k3 >= 0) oacc = fmaf(pj3, v3, oacc);
            }
        }
    }
    out[(size_t)row * DHEAD + lane] = oacc;
}

extern "C" void kernel_launch(void* const* d_in, const int* in_sizes, int n_in,
                              void* d_out, int out_size, void* d_ws, size_t ws_size,
                              hipStream_t stream) {
    const float* q = (const float*)d_in[0];
    const float* k = (const float*)d_in[1];
    const float* v = (const float*)d_in[2];
    const void*  m = d_in[3];

    float* out  = (float*)d_out;
    float* attn = out + (size_t)BATCH * SEQQ * DHEAD;

    int* flag = nullptr;
    if (ws_size >= sizeof(int)) flag = (int*)d_ws;

    // ws layout: [0,16) flag | [16, 16+S) S bf16 | [16+S, 16+S+K) K hi/lo
    const size_t S_BYTES = (size_t)BATCH * SEQQ * SEQK * 2;          // 134 MB
    const size_t K_BYTES = (size_t)BATCH * SEQK * DHEAD * 2 * 2;     // 16 MB

    unsigned short* sbuf;
    int pitch;
    bool s_in_ws = ws_size >= 16 + S_BYTES;
    if (s_in_ws) {
        sbuf  = (unsigned short*)d_ws + 8;
        pitch = SEQK;
    } else {
        sbuf  = (unsigned short*)attn;   // in-place, strided (proven R5)
        pitch = 2 * SEQK;
    }

    bool k_in_ws = s_in_ws && ws_size >= 16 + S_BYTES + K_BYTES;
    if (k_in_ws) {
        unsigned short* kbuf =
            (unsigned short*)((char*)d_ws + 16 + S_BYTES);
        // kprep + mask-format detect fused: one extra block does detect
        kprep_detect<<<(BATCH * SEQK * 8) / 256 + 1, 256, 0, stream>>>(
            k, kbuf, (const unsigned char*)m, flag);
        score_kernel_direct<<<(SEQQ / 64) * BATCH, 256, 0, stream>>>(
            q, kbuf, sbuf, pitch);
    } else {
        if (flag)
            detect_mask_fmt<<<1, 256, 0, stream>>>((const unsigned char*)m, flag);
        score_kernel_cvt<<<(SEQQ / 64) * BATCH, 256, 0, stream>>>(
            q, k, sbuf, pitch);
    }

    sparsemax_pv<<<(BATCH * SEQQ) / 4, 256, 0, stream>>>(
        v, m, flag, out, attn, sbuf, pitch);
}

// Round 8
// 646.063 us; speedup vs baseline: 1.1398x; 1.0995x over previous
//
#include <hip/hip_runtime.h>
#include <float.h>

// Sparsemax attention, fp32 in/out. B=64, Lq=Lk=1024, D=64.
// d_out = out[B,Lq,D] ++ attn[B,Lq,Lk], fp32.
//
// R13 (resubmit #3; rounds 4/6/7 all died to infra -- acquisition
// timeout x2, container failure x1 -- zero kernel data so far) =
// R10 (best verified: 638.8 us) with score restructured:
//   a) 2-PHASE PIPELINE: 64-key K tiles (16 kt), double-buffered LDS.
//      STAGE(kt+1 -> buf^1) is issued BEFORE compute(buf), so the
//      __syncthreads() vmcnt-drain lands after the MFMAs and the DMA
//      overlaps compute. (R10 was fully serial: issue->drain->compute;
//      R11 counters: MfmaUtil 4.8, VALU 7.4, HBM 31 -- all pipes idle.)
//   b) FULL-SECTOR S STORES: per kt the wave transposes its 16row x 64key
//      S-tile through a 2KB/wave LDS scratch (XOR-swizzled chunks), then
//      stores 16B/lane covering full 64B sectors per row. R11 measured
//      WRITE_SIZE 330MB vs 134MB logical (8B scattered stores -> 32B
//      sectors); this removes the ~2.5x write amplification.
//   LDS = 2x16KB (K dbuf) + 8KB (S scratch) = 40KB -> 4 blocks/CU.
//   R12's direct-from-L2 K loads REVERTED (score 110 -> 181 us: per-g
//   loads feed MFMAs with no prefetch distance; latency exposed).
// Kept: kprep(+detect) pre-swizzle (retiled to 64-key tiles), swapped
// MFMA operands, shfl-broadcast sparse PV (pv ~= 65 us, near floor).

#define BATCH    64
#define SEQQ     1024
#define SEQK     1024
#define DHEAD    64

typedef short short8 __attribute__((ext_vector_type(8)));
typedef float f32x4  __attribute__((ext_vector_type(4)));
typedef unsigned short us4v __attribute__((ext_vector_type(4)));

typedef const __attribute__((address_space(1))) unsigned int as1_cuint;
typedef __attribute__((address_space(3))) unsigned int as3_uint;
typedef __attribute__((address_space(3))) unsigned char as3_uchar;

__device__ __forceinline__ unsigned short bf16_rne(float f) {
    unsigned u = __float_as_uint(f);
    u += 0x7fffu + ((u >> 16) & 1u);
    return (unsigned short)(u >> 16);
}

__device__ __forceinline__ void cvt_hilo8(const float* fv, float scale,
                                          short8* hi, short8* lo) {
    #pragma unroll
    for (int j = 0; j < 8; ++j) {
        float f = fv[j] * scale;
        unsigned short hb = bf16_rne(f);
        float hf = __uint_as_float((unsigned)hb << 16);
        (*hi)[j] = (short)hb;
        (*lo)[j] = (short)bf16_rne(f - hf);
    }
}

// ---- standalone mask detector (fallback path only) ------------------------
__global__ void detect_mask_fmt(const unsigned char* __restrict__ m,
                                int* __restrict__ flag) {
    __shared__ int s_found;
    if (threadIdx.x == 0) s_found = 0;
    __syncthreads();
    int found = 0;
    for (int o = threadIdx.x; o < 65536; o += 256) {
        if ((o & 3) != 0 && m[o] != 0) found = 1;
    }
    if (found) atomicOr(&s_found, 1);
    __syncthreads();
    if (threadIdx.x == 0) *flag = s_found;   // 1 => bytes, 0 => int32
}

// ---- kernel 0: K -> hi/lo bf16, pre-swizzled 64-key tiles + detect --------
// kbuf tile (b,kt): 8192 ushorts = [hi: key(64) x d(64) swz][lo: same].
// off = key*64 + ((db^(key&7))*8). Last block runs the mask detector.
__global__ __launch_bounds__(256) void kprep_detect(
        const float* __restrict__ k, unsigned short* __restrict__ kbuf,
        const unsigned char* __restrict__ m, int* __restrict__ flag) {
    if (blockIdx.x == (BATCH * SEQK * 8) / 256) {
        __shared__ int s_found;
        if (threadIdx.x == 0) s_found = 0;
        __syncthreads();
        int found = 0;
        for (int o = threadIdx.x; o < 65536; o += 256) {
            if ((o & 3) != 0 && m[o] != 0) found = 1;
        }
        if (found) atomicOr(&s_found, 1);
        __syncthreads();
        if (threadIdx.x == 0) *flag = s_found;
        return;
    }

    int gid  = blockIdx.x * 256 + threadIdx.x;    // [0, 64*1024*8)
    int db   = gid & 7;
    int keyg = (gid >> 3) & 1023;
    int b    = gid >> 13;
    int kt   = keyg >> 6;        // 16 tiles of 64 keys
    int key  = keyg & 63;

    const float4* src =
        (const float4*)(k + ((size_t)b * SEQK + keyg) * DHEAD + db * 8);
    float4 f0 = src[0], f1 = src[1];
    float fv[8] = {f0.x, f0.y, f0.z, f0.w, f1.x, f1.y, f1.z, f1.w};
    short8 hi, lo;
    cvt_hilo8(fv, 1.0f, &hi, &lo);

    unsigned short* tile = kbuf + (size_t)(b * 16 + kt) * 8192;
    int off = key * 64 + ((db ^ (key & 7)) * 8);   // ushort units
    *(short8*)(tile + off)        = hi;
    *(short8*)(tile + 4096 + off) = lo;
}

// DMA one 16 KB K-tile: 4 waves x 4 calls x (64 lanes x 16 B)
__device__ __forceinline__ void stage_tile(
        const unsigned short* kb_b, int kt, unsigned short* dstbuf,
        int wave, int lane) {
    const unsigned char* gtile =
        (const unsigned char*)(kb_b + (size_t)kt * 8192);
    #pragma unroll
    for (int j = 0; j < 4; ++j) {
        unsigned off = wave * 4096 + j * 1024;     // wave-uniform
        as1_cuint* gp = (as1_cuint*)(gtile + off + lane * 16);
        as3_uint*  lp = (as3_uint*)((as3_uchar*)dstbuf + off);
        __builtin_amdgcn_global_load_lds(gp, lp, 16, 0, 0);
    }
}

// ---- kernel A (fast path): pipelined MFMA scores --------------------------
// grid 1024: x = qt*64 + b (x%8 = b%8 -> per-batch XCD pinning).
// Swapped operands: C row = key (quad*4+r), col = q (l15).
__global__ __launch_bounds__(256) void score_kernel_dma(
        const float* __restrict__ q, const unsigned short* __restrict__ kbuf,
        unsigned short* __restrict__ sbuf, int pitch) {
    const int lane = threadIdx.x & 63;
    const int wave = threadIdx.x >> 6;
    const int quad = lane >> 4;
    const int l15  = lane & 15;
    const int qt = blockIdx.x >> 6;
    const int b  = blockIdx.x & 63;

    __shared__ unsigned short klds[2][8192];                 // 2 x 16 KB
    __shared__ __align__(16) unsigned short stile[4][1024];  // 4 x 2 KB

    // Q B-frags once, scaled by 1/8, hi/lo split
    const int qg = qt * 64 + wave * 16 + l15;       // this lane's q-row
    const float* qrow = q + ((size_t)b * SEQQ + qg) * DHEAD;
    short8 a_hi[2], a_lo[2];
    #pragma unroll
    for (int kc = 0; kc < 2; ++kc) {
        const float4* src = (const float4*)(qrow + kc * 32 + quad * 8);
        float4 f0 = src[0], f1 = src[1];
        float fv[8] = {f0.x, f0.y, f0.z, f0.w, f1.x, f1.y, f1.z, f1.w};
        cvt_hilo8(fv, 0.125f, &a_hi[kc], &a_lo[kc]);
    }

    const unsigned short* kb_b = kbuf + (size_t)b * 16 * 8192;
    char* stw = (char*)&stile[wave][0];

    // prologue: stage tile 0, drain
    stage_tile(kb_b, 0, &klds[0][0], wave, lane);
    __syncthreads();

    int cur = 0;
    for (int kt = 0; kt < 16; ++kt) {
        // issue next tile's DMA FIRST -> overlaps this tile's compute
        if (kt < 15)
            stage_tile(kb_b, kt + 1, &klds[cur ^ 1][0], wave, lane);

        const unsigned short* tile = &klds[cur][0];
        #pragma unroll
        for (int g = 0; g < 4; ++g) {
            int key = g * 16 + l15;
            short8 b_hi[2], b_lo[2];
            #pragma unroll
            for (int kc = 0; kc < 2; ++kc) {
                int off = key * 64 + (((kc * 4 + quad) ^ (key & 7)) * 8);
                b_hi[kc] = *(const short8*)(tile + off);
                b_lo[kc] = *(const short8*)(tile + 4096 + off);
            }
            f32x4 acc = {0.f, 0.f, 0.f, 0.f};
            #pragma unroll
            for (int kc = 0; kc < 2; ++kc) {
                acc = __builtin_amdgcn_mfma_f32_16x16x32_bf16(b_hi[kc], a_hi[kc], acc, 0, 0, 0);
                acc = __builtin_amdgcn_mfma_f32_16x16x32_bf16(b_hi[kc], a_lo[kc], acc, 0, 0, 0);
                acc = __builtin_amdgcn_mfma_f32_16x16x32_bf16(b_lo[kc], a_hi[kc], acc, 0, 0, 0);
            }
            // lane's 4 keys (row=key) of q-row l15 -> S scratch, swizzled.
            // chunk c = byte_off/16; byte_off = g*32 + quad*8
            us4v pk;
            #pragma unroll
            for (int r = 0; r < 4; ++r) pk[r] = bf16_rne(acc[r]);
            int c = g * 2 + (quad >> 1);
            *(us4v*)(stw + l15 * 128 + ((c ^ (l15 & 7)) * 16) +
                     (quad & 1) * 8) = pk;
        }

        // store S-tile: 2 x 16B/lane, full 64B sectors per row
        // (compiler inserts the lgkmcnt wait for the ds_write->ds_read dep)
        #pragma unroll
        for (int t = 0; t < 2; ++t) {
            int rl  = (lane >> 3) + t * 8;     // local row 0..15
            int c16 = lane & 7;                // 16B chunk within row
            short8 sv = *(const short8*)(stw + rl * 128 +
                                         ((c16 ^ (rl & 7)) * 16));
            unsigned short* dst = sbuf +
                ((size_t)b * SEQQ + qt * 64 + wave * 16 + rl) * (size_t)pitch +
                kt * 64 + c16 * 8;
            *(short8*)dst = sv;
        }

        __syncthreads();   // drains the overlapped DMA; guards klds swap
        cur ^= 1;
    }
}

// ---- kernel A (fallback): cvt-in-loop version (R10 form, 128-key tiles) ---
__global__ __launch_bounds__(256) void score_kernel_cvt(
        const float* __restrict__ q, const float* __restrict__ k,
        unsigned short* __restrict__ sbuf, int pitch) {
    const int lane = threadIdx.x & 63;
    const int wave = threadIdx.x >> 6;
    const int quad = lane >> 4;
    const int l15  = lane & 15;
    const int qt = blockIdx.x >> 6;
    const int b  = blockIdx.x & 63;

    __shared__ unsigned short klds[2 * 128 * 64];

    const float* qrow =
        q + ((size_t)b * SEQQ + qt * 64 + wave * 16 + l15) * DHEAD;
    short8 a_hi[2], a_lo[2];
    #pragma unroll
    for (int kc = 0; kc < 2; ++kc) {
        const float4* src = (const float4*)(qrow + kc * 32 + quad * 8);
        float4 f0 = src[0], f1 = src[1];
        float fv[8] = {f0.x, f0.y, f0.z, f0.w, f1.x, f1.y, f1.z, f1.w};
        cvt_hilo8(fv, 0.125f, &a_hi[kc], &a_lo[kc]);
    }

    const float* kb = k + (size_t)b * SEQK * DHEAD;
    unsigned short* srowq =
        sbuf + ((size_t)b * SEQQ + qt * 64 + wave * 16 + l15) * (size_t)pitch;

    for (int kt = 0; kt < 8; ++kt) {
        __syncthreads();
        const float* kbase = kb + (size_t)kt * 128 * DHEAD;
        #pragma unroll
        for (int it = 0; it < 4; ++it) {
            int e   = threadIdx.x + 256 * it;
            int key = e >> 3, db = e & 7;
            const float4* src = (const float4*)(kbase + key * DHEAD + db * 8);
            float4 f0 = src[0], f1 = src[1];
            float fv[8] = {f0.x, f0.y, f0.z, f0.w, f1.x, f1.y, f1.z, f1.w};
            short8 hi, lo;
            cvt_hilo8(fv, 1.0f, &hi, &lo);
            int off = key * 64 + ((db ^ (key & 7)) * 8);
            *(short8*)(klds + off)        = hi;
            *(short8*)(klds + 8192 + off) = lo;
        }
        __syncthreads();

        #pragma unroll
        for (int g = 0; g < 8; ++g) {
            int key = g * 16 + l15;
            short8 b_hi[2], b_lo[2];
            #pragma unroll
            for (int kc = 0; kc < 2; ++kc) {
                int db  = kc * 4 + quad;
                int off = key * 64 + ((db ^ (key & 7)) * 8);
                b_hi[kc] = *(const short8*)(klds + off);
                b_lo[kc] = *(const short8*)(klds + 8192 + off);
            }
            f32x4 acc = {0.f, 0.f, 0.f, 0.f};
            #pragma unroll
            for (int kc = 0; kc < 2; ++kc) {
                acc = __builtin_amdgcn_mfma_f32_16x16x32_bf16(b_hi[kc], a_hi[kc], acc, 0, 0, 0);
                acc = __builtin_amdgcn_mfma_f32_16x16x32_bf16(b_hi[kc], a_lo[kc], acc, 0, 0, 0);
                acc = __builtin_amdgcn_mfma_f32_16x16x32_bf16(b_lo[kc], a_hi[kc], acc, 0, 0, 0);
            }
            us4v pk;
            #pragma unroll
            for (int r = 0; r < 4; ++r) pk[r] = bf16_rne(acc[r]);
            *(us4v*)(srowq + kt * 128 + g * 16 + quad * 4) = pk;
        }
    }
}

// ---- kernel B: sparsemax + sparse PV, one wave per row, zero LDS ----------
__global__ __launch_bounds__(256) void sparsemax_pv(
        const float* __restrict__ v, const void* __restrict__ mask,
        const int* __restrict__ fmt_flag,
        float* __restrict__ out, float* __restrict__ attn,
        const unsigned short* __restrict__ sbuf, int pitch) {
    const int lane = threadIdx.x & 63;
    const int wave = threadIdx.x >> 6;
    const int row  = blockIdx.x * 4 + wave;
    const int b    = row >> 10;
    float* arow = attn + (size_t)row * SEQK;
    const int mask_is_byte = fmt_flag ? *fmt_flag : 1;

    // lane holds keys 4*lane + 256*t + c (coalesced 8B, nontemporal)
    const us4v* s4 = (const us4v*)(sbuf + (size_t)row * (size_t)pitch);
    float s[16];
    #pragma unroll
    for (int t = 0; t < 4; ++t) {
        us4v u = __builtin_nontemporal_load(s4 + lane + 64 * t);
        s[4*t+0] = __uint_as_float((unsigned)u[0] << 16);
        s[4*t+1] = __uint_as_float((unsigned)u[1] << 16);
        s[4*t+2] = __uint_as_float((unsigned)u[2] << 16);
        s[4*t+3] = __uint_as_float((unsigned)u[3] << 16);
    }
    if (mask_is_byte) {
        const unsigned* m32 =
            (const unsigned*)((const unsigned char*)mask + (size_t)row * SEQK);
        #pragma unroll
        for (int t = 0; t < 4; ++t) {
            unsigned m = __builtin_nontemporal_load(m32 + lane + 64 * t);
            if (m & 0x000000ffu) s[4*t+0] = -FLT_MAX;
            if (m & 0x0000ff00u) s[4*t+1] = -FLT_MAX;
            if (m & 0x00ff0000u) s[4*t+2] = -FLT_MAX;
            if (m & 0xff000000u) s[4*t+3] = -FLT_MAX;
        }
    } else {
        const int* mi = (const int*)mask + (size_t)row * SEQK;
        #pragma unroll
        for (int t = 0; t < 4; ++t) {
            int m0 = __builtin_nontemporal_load(mi + 4 * (lane + 64 * t) + 0);
            int m1 = __builtin_nontemporal_load(mi + 4 * (lane + 64 * t) + 1);
            int m2 = __builtin_nontemporal_load(mi + 4 * (lane + 64 * t) + 2);
            int m3 = __builtin_nontemporal_load(mi + 4 * (lane + 64 * t) + 3);
            if (m0) s[4*t+0] = -FLT_MAX;
            if (m1) s[4*t+1] = -FLT_MAX;
            if (m2) s[4*t+2] = -FLT_MAX;
            if (m3) s[4*t+3] = -FLT_MAX;
        }
    }

    float mx = -FLT_MAX;
    #pragma unroll
    for (int i = 0; i < 16; ++i) mx = fmaxf(mx, s[i]);
    #pragma unroll
    for (int off = 32; off >= 1; off >>= 1)
        mx = fmaxf(mx, __shfl_xor(mx, off, 64));

    if (mx <= -FLT_MAX) {   // fully masked row -> zeros
        f32x4 z = {0.f, 0.f, 0.f, 0.f};
        #pragma unroll
        for (int t = 0; t < 4; ++t)
            __builtin_nontemporal_store(z, (f32x4*)arow + lane + 64 * t);
        out[(size_t)row * DHEAD + lane] = 0.f;
        return;
    }

    // Michelot: seed thr = mx-1 (tau* >= mx-1); shrinks to exact support.
    float thr = mx - 1.0f, tau = 0.f;
    int cnt_prev = -1;
    for (int it = 0; it < 32; ++it) {
        float lsum = 0.f; int lcnt = 0;
        #pragma unroll
        for (int i = 0; i < 16; ++i)
            if (s[i] > thr) { lsum += s[i]; lcnt++; }
        #pragma unroll
        for (int off = 32; off >= 1; off >>= 1) {
            lsum += __shfl_xor(lsum, off, 64);
            lcnt += __shfl_xor(lcnt, off, 64);
        }
        tau = (lsum - 1.0f) / (float)lcnt;
        if (lcnt == cnt_prev) break;
        cnt_prev = lcnt;
        thr = tau;
    }

    // p; attn NT-store
    float p[16];
    #pragma unroll
    for (int i = 0; i < 16; ++i) {
        float pv = s[i] - tau;
        p[i] = pv > 0.f ? pv : 0.f;
    }
    #pragma unroll
    for (int t = 0; t < 4; ++t) {
        f32x4 f = {p[4*t+0], p[4*t+1], p[4*t+2], p[4*t+3]};
        __builtin_nontemporal_store(f, (f32x4*)arow + lane + 64 * t);
    }

    // sparse PV: group-of-4 extraction; p broadcast via __shfl
    // (k0..k3 wave-uniform -> readlane).
    const float* vbase = v + (size_t)b * SEQK * DHEAD;
    float oacc = 0.f;
    #pragma unroll
    for (int t = 0; t < 4; ++t) {
        #pragma unroll
        for (int c = 0; c < 4; ++c) {
            int i = 4 * t + c;
            unsigned long long mb = __ballot(p[i] > 0.f);
            while (mb) {
                int k0, k1 = -1, k2 = -1, k3 = -1;
                k0 = __ffsll(mb) - 1; mb &= mb - 1;
                if (mb) { k1 = __ffsll(mb) - 1; mb &= mb - 1; }
                if (mb) { k2 = __ffsll(mb) - 1; mb &= mb - 1; }
                if (mb) { k3 = __ffsll(mb) - 1; mb &= mb - 1; }
                float pj0 = __shfl(p[i], k0);
                float v0  = vbase[(size_t)(4 * k0 + 256 * t + c) * DHEAD + lane];
                float pj1 = 0.f, pj2 = 0.f, pj3 = 0.f;
                float v1 = 0.f, v2 = 0.f, v3 = 0.f;
                if (k1 >= 0) {
                    pj1 = __shfl(p[i], k1);
                    v1  = vbase[(size_t)(4 * k1 + 256 * t + c) * DHEAD + lane];
                }
                if (k2 >= 0) {
                    pj2 = __shfl(p[i], k2);
                    v2  = vbase[(size_t)(4 * k2 + 256 * t + c) * DHEAD + lane];
                }
                if (k3 >= 0) {
                    pj3 = __shfl(p[i], k3);
                    v3  = vbase[(size_t)(4 * k3 + 256 * t + c) * DHEAD + lane];
                }
                oacc = fmaf(pj0, v0, oacc);
                if (k1 >= 0) oacc = fmaf(pj1, v1, oacc);
                if (k2 >= 0) oacc = fmaf(pj2, v2, oacc);
                if (k3 >= 0) oacc = fmaf(pj3, v3, oacc);
            }
        }
    }
    out[(size_t)row * DHEAD + lane] = oacc;
}

extern "C" void kernel_launch(void* const* d_in, const int* in_sizes, int n_in,
                              void* d_out, int out_size, void* d_ws, size_t ws_size,
                              hipStream_t stream) {
    const float* q = (const float*)d_in[0];
    const float* k = (const float*)d_in[1];
    const float* v = (const float*)d_in[2];
    const void*  m = d_in[3];

    float* out  = (float*)d_out;
    float* attn = out + (size_t)BATCH * SEQQ * DHEAD;

    int* flag = nullptr;
    if (ws_size >= sizeof(int)) flag = (int*)d_ws;

    // ws layout: [0,16) flag | [16, 16+S) S bf16 | [16+S, 16+S+K) K hi/lo
    const size_t S_BYTES = (size_t)BATCH * SEQQ * SEQK * 2;          // 134 MB
    const size_t K_BYTES = (size_t)BATCH * SEQK * DHEAD * 2 * 2;     // 16 MB

    unsigned short* sbuf;
    int pitch;
    bool s_in_ws = ws_size >= 16 + S_BYTES;
    if (s_in_ws) {
        sbuf  = (unsigned short*)d_ws + 8;
        pitch = SEQK;
    } else {
        sbuf  = (unsigned short*)attn;   // in-place, strided (proven R5)
        pitch = 2 * SEQK;
    }

    bool k_in_ws = s_in_ws && ws_size >= 16 + S_BYTES + K_BYTES;
    if (k_in_ws) {
        unsigned short* kbuf =
            (unsigned short*)((char*)d_ws + 16 + S_BYTES);
        // kprep + mask-format detect fused: one extra block does detect
        kprep_detect<<<(BATCH * SEQK * 8) / 256 + 1, 256, 0, stream>>>(
            k, kbuf, (const unsigned char*)m, flag);
        score_kernel_dma<<<(SEQQ / 64) * BATCH, 256, 0, stream>>>(
            q, kbuf, sbuf, pitch);
    } else {
        if (flag)
            detect_mask_fmt<<<1, 256, 0, stream>>>((const unsigned char*)m, flag);
        score_kernel_cvt<<<(SEQQ / 64) * BATCH, 256, 0, stream>>>(
            q, k, sbuf, pitch);
    }

    sparsemax_pv<<<(BATCH * SEQQ) / 4, 256, 0, stream>>>(
        v, m, flag, out, attn, sbuf, pitch);
}

// Round 9
// 641.964 us; speedup vs baseline: 1.1471x; 1.0064x over previous
//
#include <hip/hip_runtime.h>
#include <float.h>

// Sparsemax attention, fp32 in/out. B=64, Lq=Lk=1024, D=64.
// d_out = out[B,Lq,D] ++ attn[B,Lq,Lk], fp32.
//
// R14 = R10 (best verified: 638.8 us) with exactly two score changes:
//   a) WAVE SPLIT (qh,kh): wave w = (w>>1 = q-half, w&1 = key-half);
//      each wave computes 32 q-rows x 64 keys. Same 24 MFMA/wave/kt but
//      B-frag ds_read_b128 count HALVES (16 vs 32) -- R10's wave=qrow-group
//      made all 4 waves read identical B-frags (4x duplicated LDS reads,
//      ~25 us/CU of score's ~110). VGPR +32 for 2nd Q-frag set (still
//      well under the 128 budget for 4 blocks/CU).
//   b) STORE-AFTER-BARRIER: S-stores for kt are issued after kt+1's
//      staging barrier (from registers), so their completion overlaps the
//      next compute phase instead of being drained by vmcnt(0) each kt.
// R13's dbuf pipeline + sector-transpose measured NEUTRAL (646 vs 639:
// compiler drains vmcnt(0) at every barrier; doubled barrier count ate
// the sector gain) -- reverted to R10's serial 128-key staging.
// Kept: kprep(+detect) 128-key pre-swizzle, swapped MFMA operands,
// shfl-broadcast sparse PV (~65 us, near write floor), mask in pv.

#define BATCH    64
#define SEQQ     1024
#define SEQK     1024
#define DHEAD    64

typedef short short8 __attribute__((ext_vector_type(8)));
typedef float f32x4  __attribute__((ext_vector_type(4)));
typedef unsigned short us4v __attribute__((ext_vector_type(4)));

typedef const __attribute__((address_space(1))) unsigned int as1_cuint;
typedef __attribute__((address_space(3))) unsigned int as3_uint;
typedef __attribute__((address_space(3))) unsigned char as3_uchar;

__device__ __forceinline__ unsigned short bf16_rne(float f) {
    unsigned u = __float_as_uint(f);
    u += 0x7fffu + ((u >> 16) & 1u);
    return (unsigned short)(u >> 16);
}

__device__ __forceinline__ void cvt_hilo8(const float* fv, float scale,
                                          short8* hi, short8* lo) {
    #pragma unroll
    for (int j = 0; j < 8; ++j) {
        float f = fv[j] * scale;
        unsigned short hb = bf16_rne(f);
        float hf = __uint_as_float((unsigned)hb << 16);
        (*hi)[j] = (short)hb;
        (*lo)[j] = (short)bf16_rne(f - hf);
    }
}

// ---- standalone mask detector (fallback path only) ------------------------
__global__ void detect_mask_fmt(const unsigned char* __restrict__ m,
                                int* __restrict__ flag) {
    __shared__ int s_found;
    if (threadIdx.x == 0) s_found = 0;
    __syncthreads();
    int found = 0;
    for (int o = threadIdx.x; o < 65536; o += 256) {
        if ((o & 3) != 0 && m[o] != 0) found = 1;
    }
    if (found) atomicOr(&s_found, 1);
    __syncthreads();
    if (threadIdx.x == 0) *flag = s_found;   // 1 => bytes, 0 => int32
}

// ---- kernel 0: K -> hi/lo bf16 pre-swizzled (128-key tiles) + detect ------
// kbuf tile (b,kt): 16384 ushorts = [hi: key(128) x d(64) swz][lo: same].
// Last block (idx == 2048) runs the mask-format detector instead.
__global__ __launch_bounds__(256) void kprep_detect(
        const float* __restrict__ k, unsigned short* __restrict__ kbuf,
        const unsigned char* __restrict__ m, int* __restrict__ flag) {
    if (blockIdx.x == (BATCH * SEQK * 8) / 256) {
        __shared__ int s_found;
        if (threadIdx.x == 0) s_found = 0;
        __syncthreads();
        int found = 0;
        for (int o = threadIdx.x; o < 65536; o += 256) {
            if ((o & 3) != 0 && m[o] != 0) found = 1;
        }
        if (found) atomicOr(&s_found, 1);
        __syncthreads();
        if (threadIdx.x == 0) *flag = s_found;
        return;
    }

    int gid  = blockIdx.x * 256 + threadIdx.x;    // [0, 64*1024*8)
    int db   = gid & 7;
    int keyg = (gid >> 3) & 1023;
    int b    = gid >> 13;
    int kt   = keyg >> 7;
    int key  = keyg & 127;

    const float4* src =
        (const float4*)(k + ((size_t)b * SEQK + keyg) * DHEAD + db * 8);
    float4 f0 = src[0], f1 = src[1];
    float fv[8] = {f0.x, f0.y, f0.z, f0.w, f1.x, f1.y, f1.z, f1.w};
    short8 hi, lo;
    cvt_hilo8(fv, 1.0f, &hi, &lo);

    unsigned short* tile = kbuf + (size_t)(b * 8 + kt) * 16384;
    int off = key * 64 + ((db ^ (key & 7)) * 8);   // ushort units
    *(short8*)(tile + off)        = hi;
    *(short8*)(tile + 8192 + off) = lo;
}

// ---- kernel A (fast path): scores via MFMA, DMA-staged K ------------------
// grid 1024: x = qt*64 + b (x%8 = b%8 -> per-batch XCD pinning).
// Swapped operands: C row = key (quad*4+r), col = q (l15).
// Wave split: qh = wave>>1 (32 q-rows), kh = wave&1 (64 keys of the 128).
__global__ __launch_bounds__(256) void score_kernel_dma(
        const float* __restrict__ q, const unsigned short* __restrict__ kbuf,
        unsigned short* __restrict__ sbuf, int pitch) {
    const int lane = threadIdx.x & 63;
    const int wave = threadIdx.x >> 6;
    const int quad = lane >> 4;
    const int l15  = lane & 15;
    const int qt = blockIdx.x >> 6;
    const int b  = blockIdx.x & 63;
    const int qh = wave >> 1;
    const int kh = wave & 1;

    __shared__ unsigned short klds[2 * 128 * 64];   // 32 KB

    // Q B-frags for TWO 16-row groups, scaled by 1/8, hi/lo split
    short8 a_hi[2][2], a_lo[2][2];      // [qg][kc]
    size_t srow_base[2];
    #pragma unroll
    for (int qg = 0; qg < 2; ++qg) {
        const int qr = qt * 64 + qh * 32 + qg * 16 + l15;
        const float* qrow = q + ((size_t)b * SEQQ + qr) * DHEAD;
        #pragma unroll
        for (int kc = 0; kc < 2; ++kc) {
            const float4* src = (const float4*)(qrow + kc * 32 + quad * 8);
            float4 f0 = src[0], f1 = src[1];
            float fv[8] = {f0.x, f0.y, f0.z, f0.w, f1.x, f1.y, f1.z, f1.w};
            cvt_hilo8(fv, 0.125f, &a_hi[qg][kc], &a_lo[qg][kc]);
        }
        srow_base[qg] = ((size_t)b * SEQQ + qr) * (size_t)pitch;
    }

    us4v pk[2][4];       // deferred stores: [qg][g], kt-1's results
    int kt_prev = -1;

    for (int kt = 0; kt < 8; ++kt) {
        __syncthreads();   // prev compute done before klds overwrite
        // DMA 32 KB tile: 4 waves x 8 calls x (64 lanes x 16 B)
        const unsigned char* gtile =
            (const unsigned char*)(kbuf + (size_t)(b * 8 + kt) * 16384);
        {
            unsigned base = wave * 8192 + lane * 16;
            #pragma unroll
            for (int j = 0; j < 8; ++j) {
                unsigned off = base + j * 1024;
                as1_cuint* gp = (as1_cuint*)(gtile + off);
                as3_uint*  lp = (as3_uint*)((as3_uchar*)klds +
                                            (wave * 8192 + j * 1024));
                __builtin_amdgcn_global_load_lds(gp, lp, 16, 0, 0);
            }
        }
        __syncthreads();   // staging visible

        // store kt-1's S values now: overlaps with this kt's compute,
        // drained only at the NEXT top-of-loop barrier.
        if (kt_prev >= 0) {
            #pragma unroll
            for (int qg = 0; qg < 2; ++qg)
                #pragma unroll
                for (int g = 0; g < 4; ++g)
                    *(us4v*)(sbuf + srow_base[qg] + kt_prev * 128 +
                             kh * 64 + g * 16 + quad * 4) = pk[qg][g];
        }

        #pragma unroll
        for (int g = 0; g < 4; ++g) {
            int key = kh * 64 + g * 16 + l15;
            short8 b_hi[2], b_lo[2];
            #pragma unroll
            for (int kc = 0; kc < 2; ++kc) {
                int db  = kc * 4 + quad;
                int off = key * 64 + ((db ^ (key & 7)) * 8);
                b_hi[kc] = *(const short8*)(klds + off);
                b_lo[kc] = *(const short8*)(klds + 8192 + off);
            }
            #pragma unroll
            for (int qg = 0; qg < 2; ++qg) {
                f32x4 acc = {0.f, 0.f, 0.f, 0.f};
                #pragma unroll
                for (int kc = 0; kc < 2; ++kc) {
                    acc = __builtin_amdgcn_mfma_f32_16x16x32_bf16(b_hi[kc], a_hi[qg][kc], acc, 0, 0, 0);
                    acc = __builtin_amdgcn_mfma_f32_16x16x32_bf16(b_hi[kc], a_lo[qg][kc], acc, 0, 0, 0);
                    acc = __builtin_amdgcn_mfma_f32_16x16x32_bf16(b_lo[kc], a_hi[qg][kc], acc, 0, 0, 0);
                }
                // C layout (swapped): row = quad*4+r -> key, col = l15 -> q
                #pragma unroll
                for (int r = 0; r < 4; ++r) pk[qg][g][r] = bf16_rne(acc[r]);
            }
        }
        kt_prev = kt;
    }
    // epilogue: store the last tile's results
    #pragma unroll
    for (int qg = 0; qg < 2; ++qg)
        #pragma unroll
        for (int g = 0; g < 4; ++g)
            *(us4v*)(sbuf + srow_base[qg] + kt_prev * 128 +
                     kh * 64 + g * 16 + quad * 4) = pk[qg][g];
}

// ---- kernel A (fallback): cvt-in-loop version (R10 form) ------------------
__global__ __launch_bounds__(256) void score_kernel_cvt(
        const float* __restrict__ q, const float* __restrict__ k,
        unsigned short* __restrict__ sbuf, int pitch) {
    const int lane = threadIdx.x & 63;
    const int wave = threadIdx.x >> 6;
    const int quad = lane >> 4;
    const int l15  = lane & 15;
    const int qt = blockIdx.x >> 6;
    const int b  = blockIdx.x & 63;

    __shared__ unsigned short klds[2 * 128 * 64];

    const float* qrow =
        q + ((size_t)b * SEQQ + qt * 64 + wave * 16 + l15) * DHEAD;
    short8 a_hi[2], a_lo[2];
    #pragma unroll
    for (int kc = 0; kc < 2; ++kc) {
        const float4* src = (const float4*)(qrow + kc * 32 + quad * 8);
        float4 f0 = src[0], f1 = src[1];
        float fv[8] = {f0.x, f0.y, f0.z, f0.w, f1.x, f1.y, f1.z, f1.w};
        cvt_hilo8(fv, 0.125f, &a_hi[kc], &a_lo[kc]);
    }

    const float* kb = k + (size_t)b * SEQK * DHEAD;
    unsigned short* srowq =
        sbuf + ((size_t)b * SEQQ + qt * 64 + wave * 16 + l15) * (size_t)pitch;

    for (int kt = 0; kt < 8; ++kt) {
        __syncthreads();
        const float* kbase = kb + (size_t)kt * 128 * DHEAD;
        #pragma unroll
        for (int it = 0; it < 4; ++it) {
            int e   = threadIdx.x + 256 * it;
            int key = e >> 3, db = e & 7;
            const float4* src = (const float4*)(kbase + key * DHEAD + db * 8);
            float4 f0 = src[0], f1 = src[1];
            float fv[8] = {f0.x, f0.y, f0.z, f0.w, f1.x, f1.y, f1.z, f1.w};
            short8 hi, lo;
            cvt_hilo8(fv, 1.0f, &hi, &lo);
            int off = key * 64 + ((db ^ (key & 7)) * 8);
            *(short8*)(klds + off)        = hi;
            *(short8*)(klds + 8192 + off) = lo;
        }
        __syncthreads();

        #pragma unroll
        for (int g = 0; g < 8; ++g) {
            int key = g * 16 + l15;
            short8 b_hi[2], b_lo[2];
            #pragma unroll
            for (int kc = 0; kc < 2; ++kc) {
                int db  = kc * 4 + quad;
                int off = key * 64 + ((db ^ (key & 7)) * 8);
                b_hi[kc] = *(const short8*)(klds + off);
                b_lo[kc] = *(const short8*)(klds + 8192 + off);
            }
            f32x4 acc = {0.f, 0.f, 0.f, 0.f};
            #pragma unroll
            for (int kc = 0; kc < 2; ++kc) {
                acc = __builtin_amdgcn_mfma_f32_16x16x32_bf16(b_hi[kc], a_hi[kc], acc, 0, 0, 0);
                acc = __builtin_amdgcn_mfma_f32_16x16x32_bf16(b_hi[kc], a_lo[kc], acc, 0, 0, 0);
                acc = __builtin_amdgcn_mfma_f32_16x16x32_bf16(b_lo[kc], a_hi[kc], acc, 0, 0, 0);
            }
            us4v pk;
            #pragma unroll
            for (int r = 0; r < 4; ++r) pk[r] = bf16_rne(acc[r]);
            *(us4v*)(srowq + kt * 128 + g * 16 + quad * 4) = pk;
        }
    }
}

// ---- kernel B: sparsemax + sparse PV, one wave per row, zero LDS ----------
__global__ __launch_bounds__(256) void sparsemax_pv(
        const float* __restrict__ v, const void* __restrict__ mask,
        const int* __restrict__ fmt_flag,
        float* __restrict__ out, float* __restrict__ attn,
        const unsigned short* __restrict__ sbuf, int pitch) {
    const int lane = threadIdx.x & 63;
    const int wave = threadIdx.x >> 6;
    const int row  = blockIdx.x * 4 + wave;
    const int b    = row >> 10;
    float* arow = attn + (size_t)row * SEQK;
    const int mask_is_byte = fmt_flag ? *fmt_flag : 1;

    // lane holds keys 4*lane + 256*t + c (coalesced 8B, nontemporal)
    const us4v* s4 = (const us4v*)(sbuf + (size_t)row * (size_t)pitch);
    float s[16];
    #pragma unroll
    for (int t = 0; t < 4; ++t) {
        us4v u = __builtin_nontemporal_load(s4 + lane + 64 * t);
        s[4*t+0] = __uint_as_float((unsigned)u[0] << 16);
        s[4*t+1] = __uint_as_float((unsigned)u[1] << 16);
        s[4*t+2] = __uint_as_float((unsigned)u[2] << 16);
        s[4*t+3] = __uint_as_float((unsigned)u[3] << 16);
    }
    if (mask_is_byte) {
        const unsigned* m32 =
            (const unsigned*)((const unsigned char*)mask + (size_t)row * SEQK);
        #pragma unroll
        for (int t = 0; t < 4; ++t) {
            unsigned m = __builtin_nontemporal_load(m32 + lane + 64 * t);
            if (m & 0x000000ffu) s[4*t+0] = -FLT_MAX;
            if (m & 0x0000ff00u) s[4*t+1] = -FLT_MAX;
            if (m & 0x00ff0000u) s[4*t+2] = -FLT_MAX;
            if (m & 0xff000000u) s[4*t+3] = -FLT_MAX;
        }
    } else {
        const int* mi = (const int*)mask + (size_t)row * SEQK;
        #pragma unroll
        for (int t = 0; t < 4; ++t) {
            int m0 = __builtin_nontemporal_load(mi + 4 * (lane + 64 * t) + 0);
            int m1 = __builtin_nontemporal_load(mi + 4 * (lane + 64 * t) + 1);
            int m2 = __builtin_nontemporal_load(mi + 4 * (lane + 64 * t) + 2);
            int m3 = __builtin_nontemporal_load(mi + 4 * (lane + 64 * t) + 3);
            if (m0) s[4*t+0] = -FLT_MAX;
            if (m1) s[4*t+1] = -FLT_MAX;
            if (m2) s[4*t+2] = -FLT_MAX;
            if (m3) s[4*t+3] = -FLT_MAX;
        }
    }

    float mx = -FLT_MAX;
    #pragma unroll
    for (int i = 0; i < 16; ++i) mx = fmaxf(mx, s[i]);
    #pragma unroll
    for (int off = 32; off >= 1; off >>= 1)
        mx = fmaxf(mx, __shfl_xor(mx, off, 64));

    if (mx <= -FLT_MAX) {   // fully masked row -> zeros
        f32x4 z = {0.f, 0.f, 0.f, 0.f};
        #pragma unroll
        for (int t = 0; t < 4; ++t)
            __builtin_nontemporal_store(z, (f32x4*)arow + lane + 64 * t);
        out[(size_t)row * DHEAD + lane] = 0.f;
        return;
    }

    // Michelot: seed thr = mx-1 (tau* >= mx-1); shrinks to exact support.
    float thr = mx - 1.0f, tau = 0.f;
    int cnt_prev = -1;
    for (int it = 0; it < 32; ++it) {
        float lsum = 0.f; int lcnt = 0;
        #pragma unroll
        for (int i = 0; i < 16; ++i)
            if (s[i] > thr) { lsum += s[i]; lcnt++; }
        #pragma unroll
        for (int off = 32; off >= 1; off >>= 1) {
            lsum += __shfl_xor(lsum, off, 64);
            lcnt += __shfl_xor(lcnt, off, 64);
        }
        tau = (lsum - 1.0f) / (float)lcnt;
        if (lcnt == cnt_prev) break;
        cnt_prev = lcnt;
        thr = tau;
    }

    // p; attn NT-store
    float p[16];
    #pragma unroll
    for (int i = 0; i < 16; ++i) {
        float pv = s[i] - tau;
        p[i] = pv > 0.f ? pv : 0.f;
    }
    #pragma unroll
    for (int t = 0; t < 4; ++t) {
        f32x4 f = {p[4*t+0], p[4*t+1], p[4*t+2], p[4*t+3]};
        __builtin_nontemporal_store(f, (f32x4*)arow + lane + 64 * t);
    }

    // sparse PV: group-of-4 extraction; p broadcast via __shfl
    // (k0..k3 wave-uniform -> readlane).
    const float* vbase = v + (size_t)b * SEQK * DHEAD;
    float oacc = 0.f;
    #pragma unroll
    for (int t = 0; t < 4; ++t) {
        #pragma unroll
        for (int c = 0; c < 4; ++c) {
            int i = 4 * t + c;
            unsigned long long mb = __ballot(p[i] > 0.f);
            while (mb) {
                int k0, k1 = -1, k2 = -1, k3 = -1;
                k0 = __ffsll(mb) - 1; mb &= mb - 1;
                if (mb) { k1 = __ffsll(mb) - 1; mb &= mb - 1; }
                if (mb) { k2 = __ffsll(mb) - 1; mb &= mb - 1; }
                if (mb) { k3 = __ffsll(mb) - 1; mb &= mb - 1; }
                float pj0 = __shfl(p[i], k0);
                float v0  = vbase[(size_t)(4 * k0 + 256 * t + c) * DHEAD + lane];
                float pj1 = 0.f, pj2 = 0.f, pj3 = 0.f;
                float v1 = 0.f, v2 = 0.f, v3 = 0.f;
                if (k1 >= 0) {
                    pj1 = __shfl(p[i], k1);
                    v1  = vbase[(size_t)(4 * k1 + 256 * t + c) * DHEAD + lane];
                }
                if (k2 >= 0) {
                    pj2 = __shfl(p[i], k2);
                    v2  = vbase[(size_t)(4 * k2 + 256 * t + c) * DHEAD + lane];
                }
                if (k3 >= 0) {
                    pj3 = __shfl(p[i], k3);
                    v3  = vbase[(size_t)(4 * k3 + 256 * t + c) * DHEAD + lane];
                }
                oacc = fmaf(pj0, v0, oacc);
                if (k1 >= 0) oacc = fmaf(pj1, v1, oacc);
                if (k2 >= 0) oacc = fmaf(pj2, v2, oacc);
                if (k3 >= 0) oacc = fmaf(pj3, v3, oacc);
            }
        }
    }
    out[(size_t)row * DHEAD + lane] = oacc;
}

extern "C" void kernel_launch(void* const* d_in, const int* in_sizes, int n_in,
                              void* d_out, int out_size, void* d_ws, size_t ws_size,
                              hipStream_t stream) {
    const float* q = (const float*)d_in[0];
    const float* k = (const float*)d_in[1];
    const float* v = (const float*)d_in[2];
    const void*  m = d_in[3];

    float* out  = (float*)d_out;
    float* attn = out + (size_t)BATCH * SEQQ * DHEAD;

    int* flag = nullptr;
    if (ws_size >= sizeof(int)) flag = (int*)d_ws;

    // ws layout: [0,16) flag | [16, 16+S) S bf16 | [16+S, 16+S+K) K hi/lo
    const size_t S_BYTES = (size_t)BATCH * SEQQ * SEQK * 2;          // 134 MB
    const size_t K_BYTES = (size_t)BATCH * SEQK * DHEAD * 2 * 2;     // 16 MB

    unsigned short* sbuf;
    int pitch;
    bool s_in_ws = ws_size >= 16 + S_BYTES;
    if (s_in_ws) {
        sbuf  = (unsigned short*)d_ws + 8;
        pitch = SEQK;
    } else {
        sbuf  = (unsigned short*)attn;   // in-place, strided (proven R5)
        pitch = 2 * SEQK;
    }

    bool k_in_ws = s_in_ws && ws_size >= 16 + S_BYTES + K_BYTES;
    if (k_in_ws) {
        unsigned short* kbuf =
            (unsigned short*)((char*)d_ws + 16 + S_BYTES);
        // kprep + mask-format detect fused: one extra block does detect
        kprep_detect<<<(BATCH * SEQK * 8) / 256 + 1, 256, 0, stream>>>(
            k, kbuf, (const unsigned char*)m, flag);
        score_kernel_dma<<<(SEQQ / 64) * BATCH, 256, 0, stream>>>(
            q, kbuf, sbuf, pitch);
    } else {
        if (flag)
            detect_mask_fmt<<<1, 256, 0, stream>>>((const unsigned char*)m, flag);
        score_kernel_cvt<<<(SEQQ / 64) * BATCH, 256, 0, stream>>>(
            q, k, sbuf, pitch);
    }

    sparsemax_pv<<<(BATCH * SEQQ) / 4, 256, 0, stream>>>(
        v, m, flag, out, attn, sbuf, pitch);
}